// Round 1
// baseline (3347.886 us; speedup 1.0000x reference)
//
#include <hip/hip_runtime.h>
#include <cstdint>

// AxialAttention3D on MI355X.
// Tokens live fp32 in d_out, layout (L=13, H=48, W=96, D=512), updated in place
// by each of the three axial blocks. Workspace:
//   wT[3]  : qkv weights transposed to (N=1536, K=512) bf16   3 x 1.5 MB
//   pT     : proj weight transposed to (512,512) bf16         0.5 MB
//   stats  : per-token LN (mean, rstd) fp32                   0.46 MB
//   qkv    : (59904, 1536) bf16                               184 MB
// total ~190 MB.  Attention overwrites the q slots of qkv with its output,
// so proj reads A from qkv cols [0,512) (row stride 1536).

#define L_DIM 13
#define H_DIM 48
#define W_DIM 96
#define D_DIM 512
#define NH    16
#define MTOK  (L_DIM * H_DIM * W_DIM)   // 59904
#define N3    (3 * D_DIM)               // 1536
#define PI_F  3.14159265358979323846f

typedef __bf16 bf16x8 __attribute__((ext_vector_type(8)));
typedef float  f32x4  __attribute__((ext_vector_type(4)));

__device__ __forceinline__ float bf2f(unsigned short u) {
    return __builtin_bit_cast(float, ((unsigned)u) << 16);
}
__device__ __forceinline__ unsigned short f2bf(float f) {
    unsigned u = __builtin_bit_cast(unsigned, f);
    u += 0x7fffu + ((u >> 16) & 1u);   // round-to-nearest-even
    return (unsigned short)(u >> 16);
}

// ---------------------------------------------------------------- copy x -> tokens
__global__ __launch_bounds__(256) void copy_f4(const float4* __restrict__ src,
                                               float4* __restrict__ dst, int n4) {
    int i = blockIdx.x * 256 + threadIdx.x;
    if (i < n4) dst[i] = src[i];
}

// ---------------------------------------------------------------- W (512 x N) -> W^T (N x 512) bf16
__global__ __launch_bounds__(256) void transpose_w(const float* __restrict__ w,
                                                   unsigned short* __restrict__ wt, int N) {
    int idx = blockIdx.x * 256 + threadIdx.x;
    if (idx >= 512 * N) return;
    int n = idx >> 9, k = idx & 511;
    wt[idx] = f2bf(w[k * N + n]);
}

// ---------------------------------------------------------------- LN stats: one wave per token
__global__ __launch_bounds__(256) void ln_stats(const float* __restrict__ tok,
                                                float* __restrict__ stats) {
    int wv = threadIdx.x >> 6, lane = threadIdx.x & 63;
    int t = blockIdx.x * 4 + wv;
    const float* p = tok + (size_t)t * D_DIM;
    float s = 0.f, s2 = 0.f;
    #pragma unroll
    for (int j = 0; j < 8; ++j) { float v = p[lane + j * 64]; s += v; s2 += v * v; }
    #pragma unroll
    for (int off = 32; off; off >>= 1) {
        s  += __shfl_down(s, off, 64);
        s2 += __shfl_down(s2, off, 64);
    }
    if (lane == 0) {
        float m   = s * (1.f / 512.f);
        float var = s2 * (1.f / 512.f) - m * m;
        stats[t * 2]     = m;
        stats[t * 2 + 1] = rsqrtf(var + 1e-5f);
    }
}

// ---------------------------------------------------------------- QKV GEMM: C = LN(tok) @ W + b, bf16 out
// A = LN-on-the-fly from fp32 tokens; B = W^T (N x K) bf16; 128x128 tile, BK=64.
__global__ __launch_bounds__(256) void qkv_gemm(
    const float* __restrict__ tok, const float* __restrict__ stats,
    const float* __restrict__ g, const float* __restrict__ bln,
    const unsigned short* __restrict__ wT, const float* __restrict__ bias,
    unsigned short* __restrict__ out)
{
    __shared__ alignas(16) unsigned short As[128][72];
    __shared__ alignas(16) unsigned short Bs[128][72];
    const int m0 = blockIdx.x * 128, n0 = blockIdx.y * 128;
    const int tid = threadIdx.x, lane = tid & 63, wv = tid >> 6;
    const int wm = (wv >> 1) * 64, wn = (wv & 1) * 64;
    f32x4 acc[4][4] = {};

    for (int k0 = 0; k0 < 512; k0 += 64) {
        #pragma unroll
        for (int i = 0; i < 8; ++i) {                 // A: 128 x 64 fp32 -> LN -> bf16
            int c  = tid + i * 256;
            int r  = c >> 4;
            int cc = (c & 15) << 2;
            int gm = m0 + r;
            float4 v = *(const float4*)&tok[(size_t)gm * 512 + k0 + cc];
            float mu = stats[gm * 2], rs = stats[gm * 2 + 1];
            int col = k0 + cc;
            unsigned short* dst = &As[r][cc];
            dst[0] = f2bf((v.x - mu) * rs * g[col]     + bln[col]);
            dst[1] = f2bf((v.y - mu) * rs * g[col + 1] + bln[col + 1]);
            dst[2] = f2bf((v.z - mu) * rs * g[col + 2] + bln[col + 2]);
            dst[3] = f2bf((v.w - mu) * rs * g[col + 3] + bln[col + 3]);
        }
        #pragma unroll
        for (int i = 0; i < 4; ++i) {                 // B: 128 x 64 bf16
            int c = tid + i * 256;
            int r = c >> 3, cc = (c & 7) << 3;
            *(uint4*)&Bs[r][cc] = *(const uint4*)&wT[(size_t)(n0 + r) * 512 + k0 + cc];
        }
        __syncthreads();
        const int ko = (lane >> 4) * 8, lm = lane & 15;
        #pragma unroll
        for (int kk = 0; kk < 64; kk += 32) {
            bf16x8 af[4], bfr[4];
            #pragma unroll
            for (int mi = 0; mi < 4; ++mi) af[mi]  = *(const bf16x8*)&As[wm + mi * 16 + lm][kk + ko];
            #pragma unroll
            for (int ni = 0; ni < 4; ++ni) bfr[ni] = *(const bf16x8*)&Bs[wn + ni * 16 + lm][kk + ko];
            #pragma unroll
            for (int mi = 0; mi < 4; ++mi)
                #pragma unroll
                for (int ni = 0; ni < 4; ++ni)
                    acc[mi][ni] = __builtin_amdgcn_mfma_f32_16x16x32_bf16(af[mi], bfr[ni], acc[mi][ni], 0, 0, 0);
        }
        __syncthreads();
    }
    const int cr = (lane >> 4) * 4, ccol = lane & 15;
    #pragma unroll
    for (int ni = 0; ni < 4; ++ni) {
        int col = n0 + wn + ni * 16 + ccol;
        float bb = bias[col];
        #pragma unroll
        for (int mi = 0; mi < 4; ++mi)
            #pragma unroll
            for (int r = 0; r < 4; ++r) {
                int row = m0 + wm + mi * 16 + cr + r;
                out[(size_t)row * N3 + col] = f2bf(acc[mi][ni][r] + bb);
            }
    }
}

// ---------------------------------------------------------------- attention: one block per (seq, head)
__global__ __launch_bounds__(256) void attn_kernel(
    unsigned short* __restrict__ qkv,
    const float* __restrict__ lat_grid, const float* __restrict__ lon_grid,
    int mode, int S)
{
    __shared__ unsigned short qs[96][32];
    __shared__ unsigned short ks[96][32];
    __shared__ unsigned short vs[96][32];
    __shared__ float sc[96][96];
    const int n = blockIdx.x, h = blockIdx.y, tid = threadIdx.x;
    int base, step;
    if (mode == 0)      { int l = n / 96, w = n - l * 96; base = l * (48 * 96) + w; step = 96; }
    else if (mode == 1) { base = n * 96; step = 1; }
    else                { base = n; step = 48 * 96; }

    for (int idx = tid; idx < S * 32; idx += 256) {
        int s = idx >> 5, d = idx & 31;
        size_t o = (size_t)(base + s * step) * N3 + h * 32 + d;
        qs[s][d] = qkv[o];
        ks[s][d] = qkv[o + 512];
        vs[s][d] = qkv[o + 1024];
    }
    __syncthreads();

    if (mode < 2) {  // rotary on q,k (in-LDS, matches reference concat layout)
        float o1[12], o2[12];
        int cnt = 0;
        for (int idx = tid; idx < S * 32; idx += 256, ++cnt) {
            int s = idx >> 5, j = idx & 31, i = j & 15;
            unsigned short* bufr = (j < 16) ? &qs[s][0] : &ks[s][0];
            float x1 = bf2f(bufr[2 * i]), x2 = bf2f(bufr[2 * i + 1]);
            float coord;
            if (mode == 0) {
                float la = lat_grid[s];
                coord = fminf(fmaxf(la, -PI_F / 2 + 1e-6f), PI_F / 2 - 1e-6f);
            } else {
                float xp = lon_grid[s] + PI_F;
                coord = xp - floorf(xp * (0.5f / PI_F)) * (2.0f * PI_F) - PI_F;
            }
            float ph = coord * exp2f(-(float)i * 0.83048202372f); // log2(1e4)/16
            float sn = sinf(ph), cs = cosf(ph);
            o1[cnt] = x1 * cs - x2 * sn;
            o2[cnt] = x1 * sn + x2 * cs;
        }
        __syncthreads();
        cnt = 0;
        for (int idx = tid; idx < S * 32; idx += 256, ++cnt) {
            int s = idx >> 5, j = idx & 31, i = j & 15;
            unsigned short* bufr = (j < 16) ? &qs[s][0] : &ks[s][0];
            bufr[i]      = f2bf(o1[cnt]);
            bufr[16 + i] = f2bf(o2[cnt]);
        }
        __syncthreads();
    }

    const float scale = 0.17677669529663689f; // 1/sqrt(32)
    for (int idx = tid; idx < S * S; idx += 256) {
        int i = idx / S, j = idx - i * S;
        float a = 0.f;
        #pragma unroll
        for (int d = 0; d < 32; ++d) a += bf2f(qs[i][d]) * bf2f(ks[j][d]);
        sc[i][j] = a * scale;
    }
    __syncthreads();
    if (tid < S) {
        float mx = -1e30f;
        for (int j = 0; j < S; ++j) mx = fmaxf(mx, sc[tid][j]);
        float sum = 0.f;
        for (int j = 0; j < S; ++j) { float e = __expf(sc[tid][j] - mx); sc[tid][j] = e; sum += e; }
        float inv = 1.f / sum;
        for (int j = 0; j < S; ++j) sc[tid][j] *= inv;
    }
    __syncthreads();
    for (int idx = tid; idx < S * 32; idx += 256) {   // O = P @ V, overwrite q slot
        int i = idx >> 5, d = idx & 31;
        float a = 0.f;
        for (int j = 0; j < S; ++j) a += sc[i][j] * bf2f(vs[j][d]);
        qkv[(size_t)(base + i * step) * N3 + h * 32 + d] = f2bf(a);
    }
}

// ---------------------------------------------------------------- proj GEMM: tok += attn @ P + pb
__global__ __launch_bounds__(256) void proj_gemm(
    const unsigned short* __restrict__ attn,   // qkv buffer, cols [0,512), row stride 1536
    const unsigned short* __restrict__ pT, const float* __restrict__ pb,
    float* __restrict__ tok)
{
    __shared__ alignas(16) unsigned short As[128][72];
    __shared__ alignas(16) unsigned short Bs[128][72];
    const int m0 = blockIdx.x * 128, n0 = blockIdx.y * 128;
    const int tid = threadIdx.x, lane = tid & 63, wv = tid >> 6;
    const int wm = (wv >> 1) * 64, wn = (wv & 1) * 64;
    f32x4 acc[4][4] = {};

    for (int k0 = 0; k0 < 512; k0 += 64) {
        #pragma unroll
        for (int i = 0; i < 4; ++i) {
            int c = tid + i * 256;
            int r = c >> 3, cc = (c & 7) << 3;
            *(uint4*)&As[r][cc] = *(const uint4*)&attn[(size_t)(m0 + r) * N3 + k0 + cc];
        }
        #pragma unroll
        for (int i = 0; i < 4; ++i) {
            int c = tid + i * 256;
            int r = c >> 3, cc = (c & 7) << 3;
            *(uint4*)&Bs[r][cc] = *(const uint4*)&pT[(size_t)(n0 + r) * 512 + k0 + cc];
        }
        __syncthreads();
        const int ko = (lane >> 4) * 8, lm = lane & 15;
        #pragma unroll
        for (int kk = 0; kk < 64; kk += 32) {
            bf16x8 af[4], bfr[4];
            #pragma unroll
            for (int mi = 0; mi < 4; ++mi) af[mi]  = *(const bf16x8*)&As[wm + mi * 16 + lm][kk + ko];
            #pragma unroll
            for (int ni = 0; ni < 4; ++ni) bfr[ni] = *(const bf16x8*)&Bs[wn + ni * 16 + lm][kk + ko];
            #pragma unroll
            for (int mi = 0; mi < 4; ++mi)
                #pragma unroll
                for (int ni = 0; ni < 4; ++ni)
                    acc[mi][ni] = __builtin_amdgcn_mfma_f32_16x16x32_bf16(af[mi], bfr[ni], acc[mi][ni], 0, 0, 0);
        }
        __syncthreads();
    }
    const int cr = (lane >> 4) * 4, ccol = lane & 15;
    #pragma unroll
    for (int ni = 0; ni < 4; ++ni) {
        int col = n0 + wn + ni * 16 + ccol;
        float bb = pb[col];
        #pragma unroll
        for (int mi = 0; mi < 4; ++mi)
            #pragma unroll
            for (int r = 0; r < 4; ++r) {
                int row = m0 + wm + mi * 16 + cr + r;
                size_t a = (size_t)row * 512 + col;
                tok[a] = tok[a] + acc[mi][ni][r] + bb;   // residual in place
            }
    }
}

// ---------------------------------------------------------------- launch
extern "C" void kernel_launch(void* const* d_in, const int* in_sizes, int n_in,
                              void* d_out, int out_size, void* d_ws, size_t ws_size,
                              hipStream_t stream) {
    const float* x        = (const float*)d_in[0];
    const float* lat_grid = (const float*)d_in[1];
    const float* lon_grid = (const float*)d_in[2];
    const float* qkv_w[3] = {(const float*)d_in[3], (const float*)d_in[5], (const float*)d_in[7]};
    const float* qkv_b[3] = {(const float*)d_in[4], (const float*)d_in[6], (const float*)d_in[8]};
    const float* proj_w   = (const float*)d_in[9];
    const float* proj_b   = (const float*)d_in[10];
    const float* g[3]     = {(const float*)d_in[11], (const float*)d_in[13], (const float*)d_in[15]};
    const float* bln[3]   = {(const float*)d_in[12], (const float*)d_in[14], (const float*)d_in[16]};
    float* tok = (float*)d_out;

    unsigned short* wT0 = (unsigned short*)d_ws;
    unsigned short* wT1 = wT0 + 1536 * 512;
    unsigned short* wT2 = wT1 + 1536 * 512;
    unsigned short* pT  = wT2 + 1536 * 512;
    float*          stats = (float*)(pT + 512 * 512);
    unsigned short* qkv = (unsigned short*)(stats + 2 * MTOK);
    unsigned short* wT[3] = {wT0, wT1, wT2};

    // tokens <- x
    copy_f4<<<(MTOK * 512 / 4) / 256, 256, 0, stream>>>((const float4*)x, (float4*)tok, MTOK * 512 / 4);
    // weight transposes to bf16
    transpose_w<<<(512 * 1536) / 256, 256, 0, stream>>>(qkv_w[0], wT0, 1536);
    transpose_w<<<(512 * 1536) / 256, 256, 0, stream>>>(qkv_w[1], wT1, 1536);
    transpose_w<<<(512 * 1536) / 256, 256, 0, stream>>>(qkv_w[2], wT2, 1536);
    transpose_w<<<(512 * 512) / 256, 256, 0, stream>>>(proj_w, pT, 512);

    const int S[3]    = {H_DIM, W_DIM, L_DIM};                       // 48, 96, 13
    const int NSEQ[3] = {L_DIM * W_DIM, L_DIM * H_DIM, H_DIM * W_DIM}; // 1248, 624, 4608

    for (int b = 0; b < 3; ++b) {
        ln_stats<<<MTOK / 4, 256, 0, stream>>>(tok, stats);
        qkv_gemm<<<dim3(MTOK / 128, N3 / 128), 256, 0, stream>>>(
            tok, stats, g[b], bln[b], wT[b], qkv_b[b], qkv);
        attn_kernel<<<dim3(NSEQ[b], NH), 256, 0, stream>>>(qkv, lat_grid, lon_grid, b, S[b]);
        proj_gemm<<<dim3(MTOK / 128, 512 / 128), 256, 0, stream>>>(qkv, pT, proj_b, tok);
    }
}

// Round 2
// 1516.178 us; speedup vs baseline: 2.2081x; 2.2081x over previous
//
#include <hip/hip_runtime.h>
#include <cstdint>

// AxialAttention3D on MI355X.
// Tokens live fp32 in d_out, layout (L=13, H=48, W=96, D=512), updated in place
// by each of the three axial blocks. Workspace:
//   wT[3]  : qkv weights transposed to (N=1536, K=512) bf16   3 x 1.5 MB
//   pT     : proj weight transposed to (512,512) bf16         0.5 MB
//   stats  : per-token LN (mean, rstd) fp32                   0.46 MB
//   qkv    : (59904, 1536) bf16                               184 MB
// Attention is MFMA-based (head_dim 32 == K of one 16x16x32 mfma) and
// overwrites the q slots of qkv with its output; proj reads cols [0,512).

#define L_DIM 13
#define H_DIM 48
#define W_DIM 96
#define D_DIM 512
#define NH    16
#define MTOK  (L_DIM * H_DIM * W_DIM)   // 59904
#define N3    (3 * D_DIM)               // 1536
#define PI_F  3.14159265358979323846f

typedef __bf16 bf16x8 __attribute__((ext_vector_type(8)));
typedef float  f32x4  __attribute__((ext_vector_type(4)));

__device__ __forceinline__ float bf2f(unsigned short u) {
    return __builtin_bit_cast(float, ((unsigned)u) << 16);
}
__device__ __forceinline__ unsigned short f2bf(float f) {
    unsigned u = __builtin_bit_cast(unsigned, f);
    u += 0x7fffu + ((u >> 16) & 1u);   // round-to-nearest-even
    return (unsigned short)(u >> 16);
}

// ---------------------------------------------------------------- copy x -> tokens
__global__ __launch_bounds__(256) void copy_f4(const float4* __restrict__ src,
                                               float4* __restrict__ dst, int n4) {
    int i = blockIdx.x * 256 + threadIdx.x;
    if (i < n4) dst[i] = src[i];
}

// ---------------------------------------------------------------- W (512 x N) -> W^T (N x 512) bf16
__global__ __launch_bounds__(256) void transpose_w(const float* __restrict__ w,
                                                   unsigned short* __restrict__ wt, int N) {
    int idx = blockIdx.x * 256 + threadIdx.x;
    if (idx >= 512 * N) return;
    int n = idx >> 9, k = idx & 511;
    wt[idx] = f2bf(w[k * N + n]);
}

// ---------------------------------------------------------------- LN stats: one wave per token
__global__ __launch_bounds__(256) void ln_stats(const float* __restrict__ tok,
                                                float* __restrict__ stats) {
    int wv = threadIdx.x >> 6, lane = threadIdx.x & 63;
    int t = blockIdx.x * 4 + wv;
    const float* p = tok + (size_t)t * D_DIM;
    float s = 0.f, s2 = 0.f;
    #pragma unroll
    for (int j = 0; j < 8; ++j) { float v = p[lane + j * 64]; s += v; s2 += v * v; }
    #pragma unroll
    for (int off = 32; off; off >>= 1) {
        s  += __shfl_down(s, off, 64);
        s2 += __shfl_down(s2, off, 64);
    }
    if (lane == 0) {
        float m   = s * (1.f / 512.f);
        float var = s2 * (1.f / 512.f) - m * m;
        stats[t * 2]     = m;
        stats[t * 2 + 1] = rsqrtf(var + 1e-5f);
    }
}

// ---------------------------------------------------------------- QKV GEMM: C = LN(tok) @ W + b, bf16 out
__global__ __launch_bounds__(256) void qkv_gemm(
    const float* __restrict__ tok, const float* __restrict__ stats,
    const float* __restrict__ g, const float* __restrict__ bln,
    const unsigned short* __restrict__ wT, const float* __restrict__ bias,
    unsigned short* __restrict__ out)
{
    __shared__ alignas(16) unsigned short As[128][72];
    __shared__ alignas(16) unsigned short Bs[128][72];
    const int m0 = blockIdx.x * 128, n0 = blockIdx.y * 128;
    const int tid = threadIdx.x, lane = tid & 63, wv = tid >> 6;
    const int wm = (wv >> 1) * 64, wn = (wv & 1) * 64;
    f32x4 acc[4][4] = {};

    for (int k0 = 0; k0 < 512; k0 += 64) {
        #pragma unroll
        for (int i = 0; i < 8; ++i) {                 // A: 128 x 64 fp32 -> LN -> bf16
            int c  = tid + i * 256;
            int r  = c >> 4;
            int cc = (c & 15) << 2;
            int gm = m0 + r;
            float4 v = *(const float4*)&tok[(size_t)gm * 512 + k0 + cc];
            float mu = stats[gm * 2], rs = stats[gm * 2 + 1];
            int col = k0 + cc;
            unsigned short* dst = &As[r][cc];
            dst[0] = f2bf((v.x - mu) * rs * g[col]     + bln[col]);
            dst[1] = f2bf((v.y - mu) * rs * g[col + 1] + bln[col + 1]);
            dst[2] = f2bf((v.z - mu) * rs * g[col + 2] + bln[col + 2]);
            dst[3] = f2bf((v.w - mu) * rs * g[col + 3] + bln[col + 3]);
        }
        #pragma unroll
        for (int i = 0; i < 4; ++i) {                 // B: 128 x 64 bf16
            int c = tid + i * 256;
            int r = c >> 3, cc = (c & 7) << 3;
            *(uint4*)&Bs[r][cc] = *(const uint4*)&wT[(size_t)(n0 + r) * 512 + k0 + cc];
        }
        __syncthreads();
        const int ko = (lane >> 4) * 8, lm = lane & 15;
        #pragma unroll
        for (int kk = 0; kk < 64; kk += 32) {
            bf16x8 af[4], bfr[4];
            #pragma unroll
            for (int mi = 0; mi < 4; ++mi) af[mi]  = *(const bf16x8*)&As[wm + mi * 16 + lm][kk + ko];
            #pragma unroll
            for (int ni = 0; ni < 4; ++ni) bfr[ni] = *(const bf16x8*)&Bs[wn + ni * 16 + lm][kk + ko];
            #pragma unroll
            for (int mi = 0; mi < 4; ++mi)
                #pragma unroll
                for (int ni = 0; ni < 4; ++ni)
                    acc[mi][ni] = __builtin_amdgcn_mfma_f32_16x16x32_bf16(af[mi], bfr[ni], acc[mi][ni], 0, 0, 0);
        }
        __syncthreads();
    }
    const int cr = (lane >> 4) * 4, ccol = lane & 15;
    #pragma unroll
    for (int ni = 0; ni < 4; ++ni) {
        int col = n0 + wn + ni * 16 + ccol;
        float bb = bias[col];
        #pragma unroll
        for (int mi = 0; mi < 4; ++mi)
            #pragma unroll
            for (int r = 0; r < 4; ++r) {
                int row = m0 + wm + mi * 16 + cr + r;
                out[(size_t)row * N3 + col] = f2bf(acc[mi][ni][r] + bb);
            }
    }
}

// ---------------------------------------------------------------- MFMA attention, S in {48, 96}
// One block per (seq n, head h). 4 waves split q-row tiles; k/v shared in LDS.
// Layouts (verified via round-1 GEMM): A-frag A[m=lane&15][k=quad*8+j],
// B-frag B[k][n] with n=lane&15 holding k=quad*8+j, C/D col=lane&15 row=quad*4+reg.
template<int S, int MODE>
__global__ __launch_bounds__(256) void attn_big(
    unsigned short* __restrict__ qkv,
    const float* __restrict__ lat_grid, const float* __restrict__ lon_grid)
{
    constexpr int NQ  = S / 16;                 // 3 or 6 (S multiple of 16 here)
    constexpr int SKP = (S + 31) & ~31;         // 64 or 96 (PV K padded to 32)
    constexpr int VST = SKP + 8;                // 72 / 104: bank-friendly stride
    __shared__ alignas(16) unsigned short qs[S][40];
    __shared__ alignas(16) unsigned short ks[S][40];
    __shared__ alignas(16) unsigned short vT[32][VST];
    __shared__ alignas(16) unsigned short pb[4][16][VST];

    const int n = blockIdx.x, h = blockIdx.y;
    const int tid = threadIdx.x, lane = tid & 63, wv = tid >> 6;
    int base, step;
    if (MODE == 0) { int l = n / 96, w = n - l * 96; base = l * 4608 + w; step = 96; }
    else           { base = n * 96; step = 1; }

    const float SCALE = 0.17677669529663689f;   // 1/sqrt(32)
    for (int idx = tid; idx < S * 16; idx += 256) {
        int s = idx >> 4, i = idx & 15;
        size_t ro = (size_t)(base + s * step) * N3 + h * 32;
        unsigned qp = *(const unsigned*)(qkv + ro + 2 * i);
        unsigned kp = *(const unsigned*)(qkv + ro + 512 + 2 * i);
        unsigned vp = *(const unsigned*)(qkv + ro + 1024 + 2 * i);
        float coord;
        if (MODE == 0) {
            float la = lat_grid[s];
            coord = fminf(fmaxf(la, -PI_F / 2 + 1e-6f), PI_F / 2 - 1e-6f);
        } else {
            float xp = lon_grid[s] + PI_F;
            coord = xp - floorf(xp * (0.5f / PI_F)) * (2.f * PI_F) - PI_F;
        }
        float ph = coord * exp2f(-(float)i * 0.83048202372f); // log2(1e4)/16
        float sn = sinf(ph), cs = cosf(ph);
        float q1 = bf2f((unsigned short)qp), q2 = bf2f((unsigned short)(qp >> 16));
        float k1 = bf2f((unsigned short)kp), k2 = bf2f((unsigned short)(kp >> 16));
        qs[s][i]      = f2bf((q1 * cs - q2 * sn) * SCALE);   // scale folded into q
        qs[s][16 + i] = f2bf((q1 * sn + q2 * cs) * SCALE);
        ks[s][i]      = f2bf(k1 * cs - k2 * sn);
        ks[s][16 + i] = f2bf(k1 * sn + k2 * cs);
        vT[2 * i][s]     = (unsigned short)vp;               // V transposed, raw bf16
        vT[2 * i + 1][s] = (unsigned short)(vp >> 16);
    }
    if (SKP > S) {                               // zero V pad rows (PV K padding)
        for (int idx = tid; idx < 32 * (SKP - S); idx += 256)
            vT[idx / (SKP - S)][S + idx % (SKP - S)] = 0;
    }
    __syncthreads();

    const int lm = lane & 15, ko = (lane >> 4) * 8, q4 = (lane >> 4) * 4;
    f32x4 zero = {0.f, 0.f, 0.f, 0.f};
    bf16x8 vf[SKP / 32][2];                      // hoisted V fragments
    #pragma unroll
    for (int u2 = 0; u2 < SKP / 32; ++u2)
        #pragma unroll
        for (int nh2 = 0; nh2 < 2; ++nh2)
            vf[u2][nh2] = *(const bf16x8*)&vT[nh2 * 16 + lm][u2 * 32 + ko];
    if (SKP > S) {                               // zero P pad cols once per wave
        for (int idx = lane; idx < 16 * (SKP - S); idx += 64)
            pb[wv][idx / (SKP - S)][S + idx % (SKP - S)] = 0;
    }

    for (int t = wv; t < NQ; t += 4) {
        bf16x8 aq = *(const bf16x8*)&qs[t * 16 + lm][ko];
        f32x4 c[NQ];
        #pragma unroll
        for (int u = 0; u < NQ; ++u) {
            bf16x8 bk = *(const bf16x8*)&ks[u * 16 + lm][ko];
            c[u] = __builtin_amdgcn_mfma_f32_16x16x32_bf16(aq, bk, zero, 0, 0, 0);
        }
        float mr[4] = {-1e30f, -1e30f, -1e30f, -1e30f}, sm[4] = {0.f, 0.f, 0.f, 0.f};
        #pragma unroll
        for (int u = 0; u < NQ; ++u)
            #pragma unroll
            for (int r = 0; r < 4; ++r) mr[r] = fmaxf(mr[r], c[u][r]);
        #pragma unroll
        for (int r = 0; r < 4; ++r)
            #pragma unroll
            for (int off = 1; off < 16; off <<= 1)
                mr[r] = fmaxf(mr[r], __shfl_xor(mr[r], off, 64));
        #pragma unroll
        for (int u = 0; u < NQ; ++u)
            #pragma unroll
            for (int r = 0; r < 4; ++r) {
                float e = __expf(c[u][r] - mr[r]);
                c[u][r] = e; sm[r] += e;
            }
        #pragma unroll
        for (int r = 0; r < 4; ++r) {
            #pragma unroll
            for (int off = 1; off < 16; off <<= 1)
                sm[r] += __shfl_xor(sm[r], off, 64);
            sm[r] = 1.f / sm[r];
        }
        #pragma unroll
        for (int u = 0; u < NQ; ++u)
            #pragma unroll
            for (int r = 0; r < 4; ++r)
                pb[wv][q4 + r][u * 16 + lm] = f2bf(c[u][r] * sm[r]);
        __builtin_amdgcn_wave_barrier();         // pin P write -> P read order
        f32x4 o0 = zero, o1 = zero;
        #pragma unroll
        for (int u2 = 0; u2 < SKP / 32; ++u2) {
            bf16x8 ap = *(const bf16x8*)&pb[wv][lm][u2 * 32 + ko];
            o0 = __builtin_amdgcn_mfma_f32_16x16x32_bf16(ap, vf[u2][0], o0, 0, 0, 0);
            o1 = __builtin_amdgcn_mfma_f32_16x16x32_bf16(ap, vf[u2][1], o1, 0, 0, 0);
        }
        __builtin_amdgcn_wave_barrier();         // next iter's P writes stay after reads
        #pragma unroll
        for (int r = 0; r < 4; ++r) {
            int row = t * 16 + q4 + r;
            size_t ro = (size_t)(base + row * step) * N3 + h * 32;
            qkv[ro + lm]      = f2bf(o0[r]);
            qkv[ro + 16 + lm] = f2bf(o1[r]);
        }
    }
}

// ---------------------------------------------------------------- MFMA attention, S=13 (lev)
// One wave per (n,h) pair, 4 pairs per block, wave-private LDS slices.
__global__ __launch_bounds__(256) void attn_small(unsigned short* __restrict__ qkv)
{
    __shared__ alignas(16) unsigned short qs[4][16][40];
    __shared__ alignas(16) unsigned short ks[4][16][40];
    __shared__ alignas(16) unsigned short vT[4][32][40];
    __shared__ alignas(16) unsigned short pb[4][16][40];
    const int tid = threadIdx.x, lane = tid & 63, wv = tid >> 6;
    const int pair = blockIdx.x * 4 + wv;
    const int n = pair >> 4, h = pair & 15;
    const int base = n, step = 4608;

    for (int idx = lane; idx < 13 * 16; idx += 64) {
        int s = idx >> 4, i = idx & 15;
        size_t ro = (size_t)(base + s * step) * N3 + h * 32;
        *(unsigned*)&qs[wv][s][2 * i] = *(const unsigned*)(qkv + ro + 2 * i);
        *(unsigned*)&ks[wv][s][2 * i] = *(const unsigned*)(qkv + ro + 512 + 2 * i);
        unsigned vp = *(const unsigned*)(qkv + ro + 1024 + 2 * i);
        vT[wv][2 * i][s]     = (unsigned short)vp;
        vT[wv][2 * i + 1][s] = (unsigned short)(vp >> 16);
    }
    for (int idx = lane; idx < 32 * 19; idx += 64) {   // zero V rows 13..31
        int d = idx / 19, k = 13 + idx % 19;
        vT[wv][d][k] = 0;
    }
    for (int idx = lane; idx < 16 * 16; idx += 64)     // zero P cols 16..31
        pb[wv][idx >> 4][16 + (idx & 15)] = 0;
    __syncthreads();

    const int lm = lane & 15, ko = (lane >> 4) * 8, q4 = (lane >> 4) * 4;
    f32x4 zero = {0.f, 0.f, 0.f, 0.f};
    bf16x8 aq = *(const bf16x8*)&qs[wv][lm][ko];
    bf16x8 bk = *(const bf16x8*)&ks[wv][lm][ko];
    f32x4 c = __builtin_amdgcn_mfma_f32_16x16x32_bf16(aq, bk, zero, 0, 0, 0);
    const float SCALE = 0.17677669529663689f;
    float cf[4], mr[4], sm[4];
    bool colok = (lm < 13);
    #pragma unroll
    for (int r = 0; r < 4; ++r) {
        cf[r] = colok ? c[r] * SCALE : -1e30f;
        mr[r] = cf[r];
    }
    #pragma unroll
    for (int r = 0; r < 4; ++r)
        #pragma unroll
        for (int off = 1; off < 16; off <<= 1)
            mr[r] = fmaxf(mr[r], __shfl_xor(mr[r], off, 64));
    #pragma unroll
    for (int r = 0; r < 4; ++r) { cf[r] = __expf(cf[r] - mr[r]); sm[r] = cf[r]; }
    #pragma unroll
    for (int r = 0; r < 4; ++r) {
        #pragma unroll
        for (int off = 1; off < 16; off <<= 1)
            sm[r] += __shfl_xor(sm[r], off, 64);
        sm[r] = 1.f / sm[r];
    }
    #pragma unroll
    for (int r = 0; r < 4; ++r)
        pb[wv][q4 + r][lm] = f2bf(cf[r] * sm[r]);
    __builtin_amdgcn_wave_barrier();
    bf16x8 ap  = *(const bf16x8*)&pb[wv][lm][ko];
    bf16x8 vf0 = *(const bf16x8*)&vT[wv][lm][ko];
    bf16x8 vf1 = *(const bf16x8*)&vT[wv][16 + lm][ko];
    f32x4 o0 = __builtin_amdgcn_mfma_f32_16x16x32_bf16(ap, vf0, zero, 0, 0, 0);
    f32x4 o1 = __builtin_amdgcn_mfma_f32_16x16x32_bf16(ap, vf1, zero, 0, 0, 0);
    #pragma unroll
    for (int r = 0; r < 4; ++r) {
        int row = q4 + r;
        if (row < 13) {
            size_t ro = (size_t)(base + row * step) * N3 + h * 32;
            qkv[ro + lm]      = f2bf(o0[r]);
            qkv[ro + 16 + lm] = f2bf(o1[r]);
        }
    }
}

// ---------------------------------------------------------------- proj GEMM: tok += attn @ P + pb
__global__ __launch_bounds__(256) void proj_gemm(
    const unsigned short* __restrict__ attn,   // qkv buffer, cols [0,512), row stride 1536
    const unsigned short* __restrict__ pT, const float* __restrict__ pb,
    float* __restrict__ tok)
{
    __shared__ alignas(16) unsigned short As[128][72];
    __shared__ alignas(16) unsigned short Bs[128][72];
    const int m0 = blockIdx.x * 128, n0 = blockIdx.y * 128;
    const int tid = threadIdx.x, lane = tid & 63, wv = tid >> 6;
    const int wm = (wv >> 1) * 64, wn = (wv & 1) * 64;
    f32x4 acc[4][4] = {};

    for (int k0 = 0; k0 < 512; k0 += 64) {
        #pragma unroll
        for (int i = 0; i < 4; ++i) {
            int c = tid + i * 256;
            int r = c >> 3, cc = (c & 7) << 3;
            *(uint4*)&As[r][cc] = *(const uint4*)&attn[(size_t)(m0 + r) * N3 + k0 + cc];
        }
        #pragma unroll
        for (int i = 0; i < 4; ++i) {
            int c = tid + i * 256;
            int r = c >> 3, cc = (c & 7) << 3;
            *(uint4*)&Bs[r][cc] = *(const uint4*)&pT[(size_t)(n0 + r) * 512 + k0 + cc];
        }
        __syncthreads();
        const int ko = (lane >> 4) * 8, lm = lane & 15;
        #pragma unroll
        for (int kk = 0; kk < 64; kk += 32) {
            bf16x8 af[4], bfr[4];
            #pragma unroll
            for (int mi = 0; mi < 4; ++mi) af[mi]  = *(const bf16x8*)&As[wm + mi * 16 + lm][kk + ko];
            #pragma unroll
            for (int ni = 0; ni < 4; ++ni) bfr[ni] = *(const bf16x8*)&Bs[wn + ni * 16 + lm][kk + ko];
            #pragma unroll
            for (int mi = 0; mi < 4; ++mi)
                #pragma unroll
                for (int ni = 0; ni < 4; ++ni)
                    acc[mi][ni] = __builtin_amdgcn_mfma_f32_16x16x32_bf16(af[mi], bfr[ni], acc[mi][ni], 0, 0, 0);
        }
        __syncthreads();
    }
    const int cr = (lane >> 4) * 4, ccol = lane & 15;
    #pragma unroll
    for (int ni = 0; ni < 4; ++ni) {
        int col = n0 + wn + ni * 16 + ccol;
        float bb = pb[col];
        #pragma unroll
        for (int mi = 0; mi < 4; ++mi)
            #pragma unroll
            for (int r = 0; r < 4; ++r) {
                int row = m0 + wm + mi * 16 + cr + r;
                size_t a = (size_t)row * 512 + col;
                tok[a] = tok[a] + acc[mi][ni][r] + bb;   // residual in place
            }
    }
}

// ---------------------------------------------------------------- launch
extern "C" void kernel_launch(void* const* d_in, const int* in_sizes, int n_in,
                              void* d_out, int out_size, void* d_ws, size_t ws_size,
                              hipStream_t stream) {
    const float* x        = (const float*)d_in[0];
    const float* lat_grid = (const float*)d_in[1];
    const float* lon_grid = (const float*)d_in[2];
    const float* qkv_w[3] = {(const float*)d_in[3], (const float*)d_in[5], (const float*)d_in[7]};
    const float* qkv_b[3] = {(const float*)d_in[4], (const float*)d_in[6], (const float*)d_in[8]};
    const float* proj_w   = (const float*)d_in[9];
    const float* proj_b   = (const float*)d_in[10];
    const float* g[3]     = {(const float*)d_in[11], (const float*)d_in[13], (const float*)d_in[15]};
    const float* bln[3]   = {(const float*)d_in[12], (const float*)d_in[14], (const float*)d_in[16]};
    float* tok = (float*)d_out;

    unsigned short* wT0 = (unsigned short*)d_ws;
    unsigned short* wT1 = wT0 + 1536 * 512;
    unsigned short* wT2 = wT1 + 1536 * 512;
    unsigned short* pT  = wT2 + 1536 * 512;
    float*          stats = (float*)(pT + 512 * 512);
    unsigned short* qkv = (unsigned short*)(stats + 2 * MTOK);
    unsigned short* wT[3] = {wT0, wT1, wT2};

    copy_f4<<<(MTOK * 512 / 4) / 256, 256, 0, stream>>>((const float4*)x, (float4*)tok, MTOK * 512 / 4);
    transpose_w<<<(512 * 1536) / 256, 256, 0, stream>>>(qkv_w[0], wT0, 1536);
    transpose_w<<<(512 * 1536) / 256, 256, 0, stream>>>(qkv_w[1], wT1, 1536);
    transpose_w<<<(512 * 1536) / 256, 256, 0, stream>>>(qkv_w[2], wT2, 1536);
    transpose_w<<<(512 * 512) / 256, 256, 0, stream>>>(proj_w, pT, 512);

    for (int b = 0; b < 3; ++b) {
        ln_stats<<<MTOK / 4, 256, 0, stream>>>(tok, stats);
        qkv_gemm<<<dim3(MTOK / 128, N3 / 128), 256, 0, stream>>>(
            tok, stats, g[b], bln[b], wT[b], qkv_b[b], qkv);
        if (b == 0)
            attn_big<48, 0><<<dim3(L_DIM * W_DIM, NH), 256, 0, stream>>>(qkv, lat_grid, lon_grid);
        else if (b == 1)
            attn_big<96, 1><<<dim3(L_DIM * H_DIM, NH), 256, 0, stream>>>(qkv, lat_grid, lon_grid);
        else
            attn_small<<<(H_DIM * W_DIM * NH) / 4, 256, 0, stream>>>(qkv);
        proj_gemm<<<dim3(MTOK / 128, 512 / 128), 256, 0, stream>>>(qkv, pT, proj_b, tok);
    }
}

// Round 3
// 1384.525 us; speedup vs baseline: 2.4181x; 1.0951x over previous
//
#include <hip/hip_runtime.h>
#include <cstdint>

// AxialAttention3D on MI355X.
// Tokens live fp32 in d_out, layout (L=13, H=48, W=96, D=512), updated in place
// by each of the three axial blocks. Workspace (all ushort):
//   wT[3] : qkv weights transposed to (N=1536, K=512) bf16   3 x 1.5 MB
//   pT    : proj weight transposed to (512,512) bf16         0.5 MB
//   lnb   : LN(tok) bf16 (59904, 512)                        61 MB
//   qkv   : (59904, 1536) bf16                               184 MB
// GEMMs use global_load_lds width-16 staging (m97 structure, unpadded
// [128][64] LDS tiles). Attention is MFMA-based and overwrites the q slots
// of qkv with its output; proj reads cols [0,512) of qkv.

#define L_DIM 13
#define H_DIM 48
#define W_DIM 96
#define D_DIM 512
#define NH    16
#define MTOK  (L_DIM * H_DIM * W_DIM)   // 59904
#define N3    (3 * D_DIM)               // 1536
#define PI_F  3.14159265358979323846f

typedef __bf16 bf16x8 __attribute__((ext_vector_type(8)));
typedef float  f32x4  __attribute__((ext_vector_type(4)));

__device__ __forceinline__ float bf2f(unsigned short u) {
    return __builtin_bit_cast(float, ((unsigned)u) << 16);
}
__device__ __forceinline__ unsigned short f2bf(float f) {
    unsigned u = __builtin_bit_cast(unsigned, f);
    u += 0x7fffu + ((u >> 16) & 1u);   // round-to-nearest-even
    return (unsigned short)(u >> 16);
}
// async global->LDS, 16B per lane; lds dest = wave-uniform base + lane*16
__device__ __forceinline__ void gload16(unsigned short* lds, const unsigned short* g) {
    __builtin_amdgcn_global_load_lds(
        (const __attribute__((address_space(1))) unsigned int*)g,
        (__attribute__((address_space(3))) unsigned int*)lds, 16, 0, 0);
}

// ---------------------------------------------------------------- copy x -> tokens
__global__ __launch_bounds__(256) void copy_f4(const float4* __restrict__ src,
                                               float4* __restrict__ dst, int n4) {
    int i = blockIdx.x * 256 + threadIdx.x;
    if (i < n4) dst[i] = src[i];
}

// ---------------------------------------------------------------- W (512 x N) -> W^T (N x 512) bf16
__global__ __launch_bounds__(256) void transpose_w(const float* __restrict__ w,
                                                   unsigned short* __restrict__ wt, int N) {
    int idx = blockIdx.x * 256 + threadIdx.x;
    if (idx >= 512 * N) return;
    int n = idx >> 9, k = idx & 511;
    wt[idx] = f2bf(w[k * N + n]);
}

// ---------------------------------------------------------------- fused LN: tok fp32 -> bf16
// One wave per token; lane handles 8 contiguous cols.
__global__ __launch_bounds__(256) void ln_apply(
    const float* __restrict__ tok, const float* __restrict__ g,
    const float* __restrict__ bln, unsigned short* __restrict__ out)
{
    int wv = threadIdx.x >> 6, lane = threadIdx.x & 63;
    int t = blockIdx.x * 4 + wv;
    const float* p = tok + (size_t)t * 512 + lane * 8;
    float4 a = *(const float4*)p, b = *(const float4*)(p + 4);
    float s  = a.x + a.y + a.z + a.w + b.x + b.y + b.z + b.w;
    float s2 = a.x*a.x + a.y*a.y + a.z*a.z + a.w*a.w + b.x*b.x + b.y*b.y + b.z*b.z + b.w*b.w;
    #pragma unroll
    for (int off = 1; off < 64; off <<= 1) {
        s  += __shfl_xor(s, off, 64);
        s2 += __shfl_xor(s2, off, 64);
    }
    float mu = s * (1.f / 512.f);
    float rs = rsqrtf(s2 * (1.f / 512.f) - mu * mu + 1e-5f);
    float4 g0 = *(const float4*)(g + lane * 8),  g1 = *(const float4*)(g + lane * 8 + 4);
    float4 b0 = *(const float4*)(bln + lane * 8), b1 = *(const float4*)(bln + lane * 8 + 4);
    unsigned short o[8];
    o[0] = f2bf((a.x - mu) * rs * g0.x + b0.x);
    o[1] = f2bf((a.y - mu) * rs * g0.y + b0.y);
    o[2] = f2bf((a.z - mu) * rs * g0.z + b0.z);
    o[3] = f2bf((a.w - mu) * rs * g0.w + b0.w);
    o[4] = f2bf((b.x - mu) * rs * g1.x + b1.x);
    o[5] = f2bf((b.y - mu) * rs * g1.y + b1.y);
    o[6] = f2bf((b.z - mu) * rs * g1.z + b1.z);
    o[7] = f2bf((b.w - mu) * rs * g1.w + b1.w);
    uint4 r;
    r.x = (unsigned)o[0] | ((unsigned)o[1] << 16);
    r.y = (unsigned)o[2] | ((unsigned)o[3] << 16);
    r.z = (unsigned)o[4] | ((unsigned)o[5] << 16);
    r.w = (unsigned)o[6] | ((unsigned)o[7] << 16);
    *(uint4*)&out[(size_t)t * 512 + lane * 8] = r;
}

// ---------------------------------------------------------------- QKV GEMM: qkv = lnb @ W + b (bf16 out)
// grid (12, 468): n fastest for A-tile L2 reuse. global_load_lds staging.
__global__ __launch_bounds__(256) void qkv_gemm(
    const unsigned short* __restrict__ lnb,
    const unsigned short* __restrict__ wT, const float* __restrict__ bias,
    unsigned short* __restrict__ out)
{
    __shared__ alignas(16) unsigned short As[128][64];
    __shared__ alignas(16) unsigned short Bs[128][64];
    const int n0 = blockIdx.x * 128, m0 = blockIdx.y * 128;
    const int tid = threadIdx.x, lane = tid & 63, wv = tid >> 6;
    const int wm = (wv >> 1) * 64, wn = (wv & 1) * 64;
    const int srow = lane >> 3, scol = (lane & 7) * 8;   // staging: 8 rows x 64 cols per wave-chunk
    f32x4 acc[4][4] = {};

    for (int k0 = 0; k0 < 512; k0 += 64) {
        #pragma unroll
        for (int i = 0; i < 4; ++i) {
            int c = i * 4 + wv;                  // chunk 0..15 -> rows c*8 .. c*8+7
            int r = c * 8 + srow;
            gload16(&As[c * 8][0], &lnb[(size_t)(m0 + r) * 512 + k0 + scol]);
            gload16(&Bs[c * 8][0], &wT [(size_t)(n0 + r) * 512 + k0 + scol]);
        }
        __syncthreads();
        const int ko = (lane >> 4) * 8, lm = lane & 15;
        #pragma unroll
        for (int kk = 0; kk < 64; kk += 32) {
            bf16x8 af[4], bfr[4];
            #pragma unroll
            for (int mi = 0; mi < 4; ++mi) af[mi]  = *(const bf16x8*)&As[wm + mi * 16 + lm][kk + ko];
            #pragma unroll
            for (int ni = 0; ni < 4; ++ni) bfr[ni] = *(const bf16x8*)&Bs[wn + ni * 16 + lm][kk + ko];
            #pragma unroll
            for (int mi = 0; mi < 4; ++mi)
                #pragma unroll
                for (int ni = 0; ni < 4; ++ni)
                    acc[mi][ni] = __builtin_amdgcn_mfma_f32_16x16x32_bf16(af[mi], bfr[ni], acc[mi][ni], 0, 0, 0);
        }
        __syncthreads();
    }
    const int cr = (lane >> 4) * 4, ccol = lane & 15;
    #pragma unroll
    for (int ni = 0; ni < 4; ++ni) {
        int col = n0 + wn + ni * 16 + ccol;
        float bb = bias[col];
        #pragma unroll
        for (int mi = 0; mi < 4; ++mi)
            #pragma unroll
            for (int r = 0; r < 4; ++r) {
                int row = m0 + wm + mi * 16 + cr + r;
                out[(size_t)row * N3 + col] = f2bf(acc[mi][ni][r] + bb);
            }
    }
}

// ---------------------------------------------------------------- MFMA attention, S in {48, 96}
template<int S, int MODE>
__global__ __launch_bounds__(256) void attn_big(
    unsigned short* __restrict__ qkv,
    const float* __restrict__ lat_grid, const float* __restrict__ lon_grid)
{
    constexpr int NQ  = S / 16;
    constexpr int SKP = (S + 31) & ~31;
    constexpr int VST = SKP + 8;
    __shared__ alignas(16) unsigned short qs[S][40];
    __shared__ alignas(16) unsigned short ks[S][40];
    __shared__ alignas(16) unsigned short vT[32][VST];
    __shared__ alignas(16) unsigned short pb[4][16][VST];

    const int n = blockIdx.x, h = blockIdx.y;
    const int tid = threadIdx.x, lane = tid & 63, wv = tid >> 6;
    int base, step;
    if (MODE == 0) { int l = n / 96, w = n - l * 96; base = l * 4608 + w; step = 96; }
    else           { base = n * 96; step = 1; }

    const float SCALE = 0.17677669529663689f;   // 1/sqrt(32)
    for (int idx = tid; idx < S * 16; idx += 256) {
        int s = idx >> 4, i = idx & 15;
        size_t ro = (size_t)(base + s * step) * N3 + h * 32;
        unsigned qp = *(const unsigned*)(qkv + ro + 2 * i);
        unsigned kp = *(const unsigned*)(qkv + ro + 512 + 2 * i);
        unsigned vp = *(const unsigned*)(qkv + ro + 1024 + 2 * i);
        float coord;
        if (MODE == 0) {
            float la = lat_grid[s];
            coord = fminf(fmaxf(la, -PI_F / 2 + 1e-6f), PI_F / 2 - 1e-6f);
        } else {
            float xp = lon_grid[s] + PI_F;
            coord = xp - floorf(xp * (0.5f / PI_F)) * (2.f * PI_F) - PI_F;
        }
        float ph = coord * exp2f(-(float)i * 0.83048202372f); // log2(1e4)/16
        float sn = sinf(ph), cs = cosf(ph);
        float q1 = bf2f((unsigned short)qp), q2 = bf2f((unsigned short)(qp >> 16));
        float k1 = bf2f((unsigned short)kp), k2 = bf2f((unsigned short)(kp >> 16));
        qs[s][i]      = f2bf((q1 * cs - q2 * sn) * SCALE);
        qs[s][16 + i] = f2bf((q1 * sn + q2 * cs) * SCALE);
        ks[s][i]      = f2bf(k1 * cs - k2 * sn);
        ks[s][16 + i] = f2bf(k1 * sn + k2 * cs);
        vT[2 * i][s]     = (unsigned short)vp;
        vT[2 * i + 1][s] = (unsigned short)(vp >> 16);
    }
    if (SKP > S) {
        for (int idx = tid; idx < 32 * (SKP - S); idx += 256)
            vT[idx / (SKP - S)][S + idx % (SKP - S)] = 0;
    }
    __syncthreads();

    const int lm = lane & 15, ko = (lane >> 4) * 8, q4 = (lane >> 4) * 4;
    f32x4 zero = {0.f, 0.f, 0.f, 0.f};
    bf16x8 vf[SKP / 32][2];
    #pragma unroll
    for (int u2 = 0; u2 < SKP / 32; ++u2)
        #pragma unroll
        for (int nh2 = 0; nh2 < 2; ++nh2)
            vf[u2][nh2] = *(const bf16x8*)&vT[nh2 * 16 + lm][u2 * 32 + ko];
    if (SKP > S) {
        for (int idx = lane; idx < 16 * (SKP - S); idx += 64)
            pb[wv][idx / (SKP - S)][S + idx % (SKP - S)] = 0;
    }

    for (int t = wv; t < NQ; t += 4) {
        bf16x8 aq = *(const bf16x8*)&qs[t * 16 + lm][ko];
        f32x4 c[NQ];
        #pragma unroll
        for (int u = 0; u < NQ; ++u) {
            bf16x8 bk = *(const bf16x8*)&ks[u * 16 + lm][ko];
            c[u] = __builtin_amdgcn_mfma_f32_16x16x32_bf16(aq, bk, zero, 0, 0, 0);
        }
        float mr[4] = {-1e30f, -1e30f, -1e30f, -1e30f}, sm[4] = {0.f, 0.f, 0.f, 0.f};
        #pragma unroll
        for (int u = 0; u < NQ; ++u)
            #pragma unroll
            for (int r = 0; r < 4; ++r) mr[r] = fmaxf(mr[r], c[u][r]);
        #pragma unroll
        for (int r = 0; r < 4; ++r)
            #pragma unroll
            for (int off = 1; off < 16; off <<= 1)
                mr[r] = fmaxf(mr[r], __shfl_xor(mr[r], off, 64));
        #pragma unroll
        for (int u = 0; u < NQ; ++u)
            #pragma unroll
            for (int r = 0; r < 4; ++r) {
                float e = __expf(c[u][r] - mr[r]);
                c[u][r] = e; sm[r] += e;
            }
        #pragma unroll
        for (int r = 0; r < 4; ++r) {
            #pragma unroll
            for (int off = 1; off < 16; off <<= 1)
                sm[r] += __shfl_xor(sm[r], off, 64);
            sm[r] = 1.f / sm[r];
        }
        #pragma unroll
        for (int u = 0; u < NQ; ++u)
            #pragma unroll
            for (int r = 0; r < 4; ++r)
                pb[wv][q4 + r][u * 16 + lm] = f2bf(c[u][r] * sm[r]);
        __builtin_amdgcn_wave_barrier();
        f32x4 o0 = zero, o1 = zero;
        #pragma unroll
        for (int u2 = 0; u2 < SKP / 32; ++u2) {
            bf16x8 ap = *(const bf16x8*)&pb[wv][lm][u2 * 32 + ko];
            o0 = __builtin_amdgcn_mfma_f32_16x16x32_bf16(ap, vf[u2][0], o0, 0, 0, 0);
            o1 = __builtin_amdgcn_mfma_f32_16x16x32_bf16(ap, vf[u2][1], o1, 0, 0, 0);
        }
        __builtin_amdgcn_wave_barrier();
        #pragma unroll
        for (int r = 0; r < 4; ++r) {
            int row = t * 16 + q4 + r;
            size_t ro = (size_t)(base + row * step) * N3 + h * 32;
            qkv[ro + lm]      = f2bf(o0[r]);
            qkv[ro + 16 + lm] = f2bf(o1[r]);
        }
    }
}

// ---------------------------------------------------------------- MFMA attention, S=13 (lev)
__global__ __launch_bounds__(256) void attn_small(unsigned short* __restrict__ qkv)
{
    __shared__ alignas(16) unsigned short qs[4][16][40];
    __shared__ alignas(16) unsigned short ks[4][16][40];
    __shared__ alignas(16) unsigned short vT[4][32][40];
    __shared__ alignas(16) unsigned short pb[4][16][40];
    const int tid = threadIdx.x, lane = tid & 63, wv = tid >> 6;
    const int pair = blockIdx.x * 4 + wv;
    const int n = pair >> 4, h = pair & 15;
    const int base = n, step = 4608;

    for (int idx = lane; idx < 13 * 16; idx += 64) {
        int s = idx >> 4, i = idx & 15;
        size_t ro = (size_t)(base + s * step) * N3 + h * 32;
        *(unsigned*)&qs[wv][s][2 * i] = *(const unsigned*)(qkv + ro + 2 * i);
        *(unsigned*)&ks[wv][s][2 * i] = *(const unsigned*)(qkv + ro + 512 + 2 * i);
        unsigned vp = *(const unsigned*)(qkv + ro + 1024 + 2 * i);
        vT[wv][2 * i][s]     = (unsigned short)vp;
        vT[wv][2 * i + 1][s] = (unsigned short)(vp >> 16);
    }
    for (int idx = lane; idx < 32 * 19; idx += 64) {
        int d = idx / 19, k = 13 + idx % 19;
        vT[wv][d][k] = 0;
    }
    for (int idx = lane; idx < 16 * 16; idx += 64)
        pb[wv][idx >> 4][16 + (idx & 15)] = 0;
    __syncthreads();

    const int lm = lane & 15, ko = (lane >> 4) * 8, q4 = (lane >> 4) * 4;
    f32x4 zero = {0.f, 0.f, 0.f, 0.f};
    bf16x8 aq = *(const bf16x8*)&qs[wv][lm][ko];
    bf16x8 bk = *(const bf16x8*)&ks[wv][lm][ko];
    f32x4 c = __builtin_amdgcn_mfma_f32_16x16x32_bf16(aq, bk, zero, 0, 0, 0);
    const float SCALE = 0.17677669529663689f;
    float cf[4], mr[4], sm[4];
    bool colok = (lm < 13);
    #pragma unroll
    for (int r = 0; r < 4; ++r) {
        cf[r] = colok ? c[r] * SCALE : -1e30f;
        mr[r] = cf[r];
    }
    #pragma unroll
    for (int r = 0; r < 4; ++r)
        #pragma unroll
        for (int off = 1; off < 16; off <<= 1)
            mr[r] = fmaxf(mr[r], __shfl_xor(mr[r], off, 64));
    #pragma unroll
    for (int r = 0; r < 4; ++r) { cf[r] = __expf(cf[r] - mr[r]); sm[r] = cf[r]; }
    #pragma unroll
    for (int r = 0; r < 4; ++r) {
        #pragma unroll
        for (int off = 1; off < 16; off <<= 1)
            sm[r] += __shfl_xor(sm[r], off, 64);
        sm[r] = 1.f / sm[r];
    }
    #pragma unroll
    for (int r = 0; r < 4; ++r)
        pb[wv][q4 + r][lm] = f2bf(cf[r] * sm[r]);
    __builtin_amdgcn_wave_barrier();
    bf16x8 ap  = *(const bf16x8*)&pb[wv][lm][ko];
    bf16x8 vf0 = *(const bf16x8*)&vT[wv][lm][ko];
    bf16x8 vf1 = *(const bf16x8*)&vT[wv][16 + lm][ko];
    f32x4 o0 = __builtin_amdgcn_mfma_f32_16x16x32_bf16(ap, vf0, zero, 0, 0, 0);
    f32x4 o1 = __builtin_amdgcn_mfma_f32_16x16x32_bf16(ap, vf1, zero, 0, 0, 0);
    #pragma unroll
    for (int r = 0; r < 4; ++r) {
        int row = q4 + r;
        if (row < 13) {
            size_t ro = (size_t)(base + row * step) * N3 + h * 32;
            qkv[ro + lm]      = f2bf(o0[r]);
            qkv[ro + 16 + lm] = f2bf(o1[r]);
        }
    }
}

// ---------------------------------------------------------------- proj GEMM: tok += attn @ P + pb
// grid (4, 468): n fastest. global_load_lds staging; A row stride is N3.
__global__ __launch_bounds__(256) void proj_gemm(
    const unsigned short* __restrict__ attn,   // qkv buffer, cols [0,512), row stride 1536
    const unsigned short* __restrict__ pT, const float* __restrict__ pb,
    float* __restrict__ tok)
{
    __shared__ alignas(16) unsigned short As[128][64];
    __shared__ alignas(16) unsigned short Bs[128][64];
    const int n0 = blockIdx.x * 128, m0 = blockIdx.y * 128;
    const int tid = threadIdx.x, lane = tid & 63, wv = tid >> 6;
    const int wm = (wv >> 1) * 64, wn = (wv & 1) * 64;
    const int srow = lane >> 3, scol = (lane & 7) * 8;
    f32x4 acc[4][4] = {};

    for (int k0 = 0; k0 < 512; k0 += 64) {
        #pragma unroll
        for (int i = 0; i < 4; ++i) {
            int c = i * 4 + wv;
            int r = c * 8 + srow;
            gload16(&As[c * 8][0], &attn[(size_t)(m0 + r) * N3 + k0 + scol]);
            gload16(&Bs[c * 8][0], &pT [(size_t)(n0 + r) * 512 + k0 + scol]);
        }
        __syncthreads();
        const int ko = (lane >> 4) * 8, lm = lane & 15;
        #pragma unroll
        for (int kk = 0; kk < 64; kk += 32) {
            bf16x8 af[4], bfr[4];
            #pragma unroll
            for (int mi = 0; mi < 4; ++mi) af[mi]  = *(const bf16x8*)&As[wm + mi * 16 + lm][kk + ko];
            #pragma unroll
            for (int ni = 0; ni < 4; ++ni) bfr[ni] = *(const bf16x8*)&Bs[wn + ni * 16 + lm][kk + ko];
            #pragma unroll
            for (int mi = 0; mi < 4; ++mi)
                #pragma unroll
                for (int ni = 0; ni < 4; ++ni)
                    acc[mi][ni] = __builtin_amdgcn_mfma_f32_16x16x32_bf16(af[mi], bfr[ni], acc[mi][ni], 0, 0, 0);
        }
        __syncthreads();
    }
    const int cr = (lane >> 4) * 4, ccol = lane & 15;
    #pragma unroll
    for (int ni = 0; ni < 4; ++ni) {
        int col = n0 + wn + ni * 16 + ccol;
        float bb = pb[col];
        #pragma unroll
        for (int mi = 0; mi < 4; ++mi)
            #pragma unroll
            for (int r = 0; r < 4; ++r) {
                int row = m0 + wm + mi * 16 + cr + r;
                size_t a = (size_t)row * 512 + col;
                tok[a] = tok[a] + acc[mi][ni][r] + bb;   // residual in place
            }
    }
}

// ---------------------------------------------------------------- launch
extern "C" void kernel_launch(void* const* d_in, const int* in_sizes, int n_in,
                              void* d_out, int out_size, void* d_ws, size_t ws_size,
                              hipStream_t stream) {
    const float* x        = (const float*)d_in[0];
    const float* lat_grid = (const float*)d_in[1];
    const float* lon_grid = (const float*)d_in[2];
    const float* qkv_w[3] = {(const float*)d_in[3], (const float*)d_in[5], (const float*)d_in[7]};
    const float* qkv_b[3] = {(const float*)d_in[4], (const float*)d_in[6], (const float*)d_in[8]};
    const float* proj_w   = (const float*)d_in[9];
    const float* proj_b   = (const float*)d_in[10];
    const float* g[3]     = {(const float*)d_in[11], (const float*)d_in[13], (const float*)d_in[15]};
    const float* bln[3]   = {(const float*)d_in[12], (const float*)d_in[14], (const float*)d_in[16]};
    float* tok = (float*)d_out;

    unsigned short* wT0 = (unsigned short*)d_ws;
    unsigned short* wT1 = wT0 + 1536 * 512;
    unsigned short* wT2 = wT1 + 1536 * 512;
    unsigned short* pT  = wT2 + 1536 * 512;
    unsigned short* lnb = pT + 512 * 512;
    unsigned short* qkv = lnb + (size_t)MTOK * 512;
    unsigned short* wT[3] = {wT0, wT1, wT2};

    copy_f4<<<(MTOK * 512 / 4) / 256, 256, 0, stream>>>((const float4*)x, (float4*)tok, MTOK * 512 / 4);
    transpose_w<<<(512 * 1536) / 256, 256, 0, stream>>>(qkv_w[0], wT0, 1536);
    transpose_w<<<(512 * 1536) / 256, 256, 0, stream>>>(qkv_w[1], wT1, 1536);
    transpose_w<<<(512 * 1536) / 256, 256, 0, stream>>>(qkv_w[2], wT2, 1536);
    transpose_w<<<(512 * 512) / 256, 256, 0, stream>>>(proj_w, pT, 512);

    for (int b = 0; b < 3; ++b) {
        ln_apply<<<MTOK / 4, 256, 0, stream>>>(tok, g[b], bln[b], lnb);
        qkv_gemm<<<dim3(N3 / 128, MTOK / 128), 256, 0, stream>>>(lnb, wT[b], qkv_b[b], qkv);
        if (b == 0)
            attn_big<48, 0><<<dim3(L_DIM * W_DIM, NH), 256, 0, stream>>>(qkv, lat_grid, lon_grid);
        else if (b == 1)
            attn_big<96, 1><<<dim3(L_DIM * H_DIM, NH), 256, 0, stream>>>(qkv, lat_grid, lon_grid);
        else
            attn_small<<<(H_DIM * W_DIM * NH) / 4, 256, 0, stream>>>(qkv);
        proj_gemm<<<dim3(512 / 128, MTOK / 128), 256, 0, stream>>>(qkv, pT, proj_b, tok);
    }
}

// Round 4
// 1235.794 us; speedup vs baseline: 2.7091x; 1.1204x over previous
//
#include <hip/hip_runtime.h>
#include <cstdint>

// AxialAttention3D on MI355X.
// Tokens live fp32 in d_out, layout (L=13, H=48, W=96, D=512), updated in place
// by each of the three axial blocks. Workspace (all ushort):
//   wT[3] : qkv weights transposed to (N=1536, K=512) bf16   3 x 1.5 MB
//   pT    : proj weight transposed to (512,512) bf16         0.5 MB
//   lnb   : LN(tok) bf16 (59904, 512)                        61 MB
//   qkv   : (59904, 1536) bf16                               184 MB
// GEMMs: global_load_lds width-16 staging into unpadded [128][64] tiles with
// XOR-swizzled granules (LDS row r holds 16B granule g at slot g^(r&7)) so
// fragment ds_read_b128 is bank-conflict-free. Attention is MFMA-based and
// overwrites the q slots of qkv; proj reads cols [0,512) of qkv.

#define L_DIM 13
#define H_DIM 48
#define W_DIM 96
#define D_DIM 512
#define NH    16
#define MTOK  (L_DIM * H_DIM * W_DIM)   // 59904
#define N3    (3 * D_DIM)               // 1536
#define PI_F  3.14159265358979323846f

typedef __bf16 bf16x8 __attribute__((ext_vector_type(8)));
typedef float  f32x4  __attribute__((ext_vector_type(4)));

__device__ __forceinline__ float bf2f(unsigned short u) {
    return __builtin_bit_cast(float, ((unsigned)u) << 16);
}
__device__ __forceinline__ unsigned short f2bf(float f) {
    unsigned u = __builtin_bit_cast(unsigned, f);
    u += 0x7fffu + ((u >> 16) & 1u);   // round-to-nearest-even
    return (unsigned short)(u >> 16);
}
// async global->LDS, 16B per lane; lds dest = wave-uniform base + lane*16
__device__ __forceinline__ void gload16(unsigned short* lds, const unsigned short* g) {
    __builtin_amdgcn_global_load_lds(
        (const __attribute__((address_space(1))) unsigned int*)g,
        (__attribute__((address_space(3))) unsigned int*)lds, 16, 0, 0);
}

// ---------------------------------------------------------------- W (512 x N) -> W^T (N x 512) bf16
// LDS-tiled 64x64: coalesced reads AND writes.
__global__ __launch_bounds__(256) void transpose_w(const float* __restrict__ w,
                                                   unsigned short* __restrict__ wt, int N) {
    __shared__ unsigned short t[64][65];
    const int k0 = blockIdx.x * 64, n0 = blockIdx.y * 64;
    const int tid = threadIdx.x;
    #pragma unroll
    for (int j = 0; j < 16; ++j) {
        int lin = j * 256 + tid;
        int kr = lin >> 6, nc = lin & 63;
        t[kr][nc] = f2bf(w[(size_t)(k0 + kr) * N + n0 + nc]);
    }
    __syncthreads();
    #pragma unroll
    for (int j = 0; j < 16; ++j) {
        int lin = j * 256 + tid;
        int nr = lin >> 6, kc = lin & 63;
        wt[(size_t)(n0 + nr) * 512 + k0 + kc] = t[kc][nr];
    }
}

// ---------------------------------------------------------------- fused LN: src fp32 -> bf16
// One wave per token; lane handles 8 contiguous cols.
__global__ __launch_bounds__(256) void ln_apply(
    const float* __restrict__ src, const float* __restrict__ g,
    const float* __restrict__ bln, unsigned short* __restrict__ out)
{
    int wv = threadIdx.x >> 6, lane = threadIdx.x & 63;
    int t = blockIdx.x * 4 + wv;
    const float* p = src + (size_t)t * 512 + lane * 8;
    float4 a = *(const float4*)p, b = *(const float4*)(p + 4);
    float s  = a.x + a.y + a.z + a.w + b.x + b.y + b.z + b.w;
    float s2 = a.x*a.x + a.y*a.y + a.z*a.z + a.w*a.w + b.x*b.x + b.y*b.y + b.z*b.z + b.w*b.w;
    #pragma unroll
    for (int off = 1; off < 64; off <<= 1) {
        s  += __shfl_xor(s, off, 64);
        s2 += __shfl_xor(s2, off, 64);
    }
    float mu = s * (1.f / 512.f);
    float rs = rsqrtf(s2 * (1.f / 512.f) - mu * mu + 1e-5f);
    float4 g0 = *(const float4*)(g + lane * 8),  g1 = *(const float4*)(g + lane * 8 + 4);
    float4 b0 = *(const float4*)(bln + lane * 8), b1 = *(const float4*)(bln + lane * 8 + 4);
    unsigned short o[8];
    o[0] = f2bf((a.x - mu) * rs * g0.x + b0.x);
    o[1] = f2bf((a.y - mu) * rs * g0.y + b0.y);
    o[2] = f2bf((a.z - mu) * rs * g0.z + b0.z);
    o[3] = f2bf((a.w - mu) * rs * g0.w + b0.w);
    o[4] = f2bf((b.x - mu) * rs * g1.x + b1.x);
    o[5] = f2bf((b.y - mu) * rs * g1.y + b1.y);
    o[6] = f2bf((b.z - mu) * rs * g1.z + b1.z);
    o[7] = f2bf((b.w - mu) * rs * g1.w + b1.w);
    uint4 r;
    r.x = (unsigned)o[0] | ((unsigned)o[1] << 16);
    r.y = (unsigned)o[2] | ((unsigned)o[3] << 16);
    r.z = (unsigned)o[4] | ((unsigned)o[5] << 16);
    r.w = (unsigned)o[6] | ((unsigned)o[7] << 16);
    *(uint4*)&out[(size_t)t * 512 + lane * 8] = r;
}

// ---------------------------------------------------------------- QKV GEMM: qkv = lnb @ W + b (bf16 out)
// grid (12, 468): n fastest for A-tile L2 reuse. Swizzled global_load_lds staging.
__global__ __launch_bounds__(256) void qkv_gemm(
    const unsigned short* __restrict__ lnb,
    const unsigned short* __restrict__ wT, const float* __restrict__ bias,
    unsigned short* __restrict__ out)
{
    __shared__ alignas(16) unsigned short As[128][64];
    __shared__ alignas(16) unsigned short Bs[128][64];
    const int n0 = blockIdx.x * 128, m0 = blockIdx.y * 128;
    const int tid = threadIdx.x, lane = tid & 63, wv = tid >> 6;
    const int wm = (wv >> 1) * 64, wn = (wv & 1) * 64;
    const int srow = lane >> 3;
    const int scol = (((lane & 7) ^ srow) << 3);   // XOR-swizzled source granule
    f32x4 acc[4][4] = {};

    for (int k0 = 0; k0 < 512; k0 += 64) {
        #pragma unroll
        for (int i = 0; i < 4; ++i) {
            int c = i * 4 + wv;                  // chunk 0..15 -> rows c*8 .. c*8+7
            int r = c * 8 + srow;
            gload16(&As[c * 8][0], &lnb[(size_t)(m0 + r) * 512 + k0 + scol]);
            gload16(&Bs[c * 8][0], &wT [(size_t)(n0 + r) * 512 + k0 + scol]);
        }
        __syncthreads();
        const int ko = (lane >> 4) * 8, lm = lane & 15, sw = lm & 7;
        #pragma unroll
        for (int kk = 0; kk < 64; kk += 32) {
            const int cA = ((((kk + ko) >> 3) ^ sw) << 3);
            bf16x8 af[4], bfr[4];
            #pragma unroll
            for (int mi = 0; mi < 4; ++mi) af[mi]  = *(const bf16x8*)&As[wm + mi * 16 + lm][cA];
            #pragma unroll
            for (int ni = 0; ni < 4; ++ni) bfr[ni] = *(const bf16x8*)&Bs[wn + ni * 16 + lm][cA];
            #pragma unroll
            for (int mi = 0; mi < 4; ++mi)
                #pragma unroll
                for (int ni = 0; ni < 4; ++ni)
                    acc[mi][ni] = __builtin_amdgcn_mfma_f32_16x16x32_bf16(af[mi], bfr[ni], acc[mi][ni], 0, 0, 0);
        }
        __syncthreads();
    }
    const int cr = (lane >> 4) * 4, ccol = lane & 15;
    #pragma unroll
    for (int ni = 0; ni < 4; ++ni) {
        int col = n0 + wn + ni * 16 + ccol;
        float bb = bias[col];
        #pragma unroll
        for (int mi = 0; mi < 4; ++mi)
            #pragma unroll
            for (int r = 0; r < 4; ++r) {
                int row = m0 + wm + mi * 16 + cr + r;
                out[(size_t)row * N3 + col] = f2bf(acc[mi][ni][r] + bb);
            }
    }
}

// ---------------------------------------------------------------- MFMA attention, S in {48, 96}
template<int S, int MODE>
__global__ __launch_bounds__(256) void attn_big(
    unsigned short* __restrict__ qkv,
    const float* __restrict__ lat_grid, const float* __restrict__ lon_grid)
{
    constexpr int NQ  = S / 16;
    constexpr int SKP = (S + 31) & ~31;
    constexpr int VST = SKP + 8;
    __shared__ alignas(16) unsigned short qs[S][40];
    __shared__ alignas(16) unsigned short ks[S][40];
    __shared__ alignas(16) unsigned short vT[32][VST];
    __shared__ alignas(16) unsigned short pb[4][16][VST];

    const int n = blockIdx.x, h = blockIdx.y;
    const int tid = threadIdx.x, lane = tid & 63, wv = tid >> 6;
    int base, step;
    if (MODE == 0) { int l = n / 96, w = n - l * 96; base = l * 4608 + w; step = 96; }
    else           { base = n * 96; step = 1; }

    const float SCALE = 0.17677669529663689f;   // 1/sqrt(32)
    for (int idx = tid; idx < S * 16; idx += 256) {
        int s = idx >> 4, i = idx & 15;
        size_t ro = (size_t)(base + s * step) * N3 + h * 32;
        unsigned qp = *(const unsigned*)(qkv + ro + 2 * i);
        unsigned kp = *(const unsigned*)(qkv + ro + 512 + 2 * i);
        unsigned vp = *(const unsigned*)(qkv + ro + 1024 + 2 * i);
        float coord;
        if (MODE == 0) {
            float la = lat_grid[s];
            coord = fminf(fmaxf(la, -PI_F / 2 + 1e-6f), PI_F / 2 - 1e-6f);
        } else {
            float xp = lon_grid[s] + PI_F;
            coord = xp - floorf(xp * (0.5f / PI_F)) * (2.f * PI_F) - PI_F;
        }
        float ph = coord * exp2f(-(float)i * 0.83048202372f); // log2(1e4)/16
        float sn = sinf(ph), cs = cosf(ph);
        float q1 = bf2f((unsigned short)qp), q2 = bf2f((unsigned short)(qp >> 16));
        float k1 = bf2f((unsigned short)kp), k2 = bf2f((unsigned short)(kp >> 16));
        qs[s][i]      = f2bf((q1 * cs - q2 * sn) * SCALE);
        qs[s][16 + i] = f2bf((q1 * sn + q2 * cs) * SCALE);
        ks[s][i]      = f2bf(k1 * cs - k2 * sn);
        ks[s][16 + i] = f2bf(k1 * sn + k2 * cs);
        vT[2 * i][s]     = (unsigned short)vp;
        vT[2 * i + 1][s] = (unsigned short)(vp >> 16);
    }
    if (SKP > S) {
        for (int idx = tid; idx < 32 * (SKP - S); idx += 256)
            vT[idx / (SKP - S)][S + idx % (SKP - S)] = 0;
    }
    __syncthreads();

    const int lm = lane & 15, ko = (lane >> 4) * 8, q4 = (lane >> 4) * 4;
    f32x4 zero = {0.f, 0.f, 0.f, 0.f};
    bf16x8 vf[SKP / 32][2];
    #pragma unroll
    for (int u2 = 0; u2 < SKP / 32; ++u2)
        #pragma unroll
        for (int nh2 = 0; nh2 < 2; ++nh2)
            vf[u2][nh2] = *(const bf16x8*)&vT[nh2 * 16 + lm][u2 * 32 + ko];
    if (SKP > S) {
        for (int idx = lane; idx < 16 * (SKP - S); idx += 64)
            pb[wv][idx / (SKP - S)][S + idx % (SKP - S)] = 0;
    }

    for (int t = wv; t < NQ; t += 4) {
        bf16x8 aq = *(const bf16x8*)&qs[t * 16 + lm][ko];
        f32x4 c[NQ];
        #pragma unroll
        for (int u = 0; u < NQ; ++u) {
            bf16x8 bk = *(const bf16x8*)&ks[u * 16 + lm][ko];
            c[u] = __builtin_amdgcn_mfma_f32_16x16x32_bf16(aq, bk, zero, 0, 0, 0);
        }
        float mr[4] = {-1e30f, -1e30f, -1e30f, -1e30f}, sm[4] = {0.f, 0.f, 0.f, 0.f};
        #pragma unroll
        for (int u = 0; u < NQ; ++u)
            #pragma unroll
            for (int r = 0; r < 4; ++r) mr[r] = fmaxf(mr[r], c[u][r]);
        #pragma unroll
        for (int r = 0; r < 4; ++r)
            #pragma unroll
            for (int off = 1; off < 16; off <<= 1)
                mr[r] = fmaxf(mr[r], __shfl_xor(mr[r], off, 64));
        #pragma unroll
        for (int u = 0; u < NQ; ++u)
            #pragma unroll
            for (int r = 0; r < 4; ++r) {
                float e = __expf(c[u][r] - mr[r]);
                c[u][r] = e; sm[r] += e;
            }
        #pragma unroll
        for (int r = 0; r < 4; ++r) {
            #pragma unroll
            for (int off = 1; off < 16; off <<= 1)
                sm[r] += __shfl_xor(sm[r], off, 64);
            sm[r] = 1.f / sm[r];
        }
        #pragma unroll
        for (int u = 0; u < NQ; ++u)
            #pragma unroll
            for (int r = 0; r < 4; ++r)
                pb[wv][q4 + r][u * 16 + lm] = f2bf(c[u][r] * sm[r]);
        __builtin_amdgcn_wave_barrier();
        f32x4 o0 = zero, o1 = zero;
        #pragma unroll
        for (int u2 = 0; u2 < SKP / 32; ++u2) {
            bf16x8 ap = *(const bf16x8*)&pb[wv][lm][u2 * 32 + ko];
            o0 = __builtin_amdgcn_mfma_f32_16x16x32_bf16(ap, vf[u2][0], o0, 0, 0, 0);
            o1 = __builtin_amdgcn_mfma_f32_16x16x32_bf16(ap, vf[u2][1], o1, 0, 0, 0);
        }
        __builtin_amdgcn_wave_barrier();
        #pragma unroll
        for (int r = 0; r < 4; ++r) {
            int row = t * 16 + q4 + r;
            size_t ro = (size_t)(base + row * step) * N3 + h * 32;
            qkv[ro + lm]      = f2bf(o0[r]);
            qkv[ro + 16 + lm] = f2bf(o1[r]);
        }
    }
}

// ---------------------------------------------------------------- MFMA attention, S=13 (lev)
__global__ __launch_bounds__(256) void attn_small(unsigned short* __restrict__ qkv)
{
    __shared__ alignas(16) unsigned short qs[4][16][40];
    __shared__ alignas(16) unsigned short ks[4][16][40];
    __shared__ alignas(16) unsigned short vT[4][32][40];
    __shared__ alignas(16) unsigned short pb[4][16][40];
    const int tid = threadIdx.x, lane = tid & 63, wv = tid >> 6;
    const int pair = blockIdx.x * 4 + wv;
    const int n = pair >> 4, h = pair & 15;
    const int base = n, step = 4608;

    for (int idx = lane; idx < 13 * 16; idx += 64) {
        int s = idx >> 4, i = idx & 15;
        size_t ro = (size_t)(base + s * step) * N3 + h * 32;
        *(unsigned*)&qs[wv][s][2 * i] = *(const unsigned*)(qkv + ro + 2 * i);
        *(unsigned*)&ks[wv][s][2 * i] = *(const unsigned*)(qkv + ro + 512 + 2 * i);
        unsigned vp = *(const unsigned*)(qkv + ro + 1024 + 2 * i);
        vT[wv][2 * i][s]     = (unsigned short)vp;
        vT[wv][2 * i + 1][s] = (unsigned short)(vp >> 16);
    }
    for (int idx = lane; idx < 32 * 19; idx += 64) {
        int d = idx / 19, k = 13 + idx % 19;
        vT[wv][d][k] = 0;
    }
    for (int idx = lane; idx < 16 * 16; idx += 64)
        pb[wv][idx >> 4][16 + (idx & 15)] = 0;
    __syncthreads();

    const int lm = lane & 15, ko = (lane >> 4) * 8, q4 = (lane >> 4) * 4;
    f32x4 zero = {0.f, 0.f, 0.f, 0.f};
    bf16x8 aq = *(const bf16x8*)&qs[wv][lm][ko];
    bf16x8 bk = *(const bf16x8*)&ks[wv][lm][ko];
    f32x4 c = __builtin_amdgcn_mfma_f32_16x16x32_bf16(aq, bk, zero, 0, 0, 0);
    const float SCALE = 0.17677669529663689f;
    float cf[4], mr[4], sm[4];
    bool colok = (lm < 13);
    #pragma unroll
    for (int r = 0; r < 4; ++r) {
        cf[r] = colok ? c[r] * SCALE : -1e30f;
        mr[r] = cf[r];
    }
    #pragma unroll
    for (int r = 0; r < 4; ++r)
        #pragma unroll
        for (int off = 1; off < 16; off <<= 1)
            mr[r] = fmaxf(mr[r], __shfl_xor(mr[r], off, 64));
    #pragma unroll
    for (int r = 0; r < 4; ++r) { cf[r] = __expf(cf[r] - mr[r]); sm[r] = cf[r]; }
    #pragma unroll
    for (int r = 0; r < 4; ++r) {
        #pragma unroll
        for (int off = 1; off < 16; off <<= 1)
            sm[r] += __shfl_xor(sm[r], off, 64);
        sm[r] = 1.f / sm[r];
    }
    #pragma unroll
    for (int r = 0; r < 4; ++r)
        pb[wv][q4 + r][lm] = f2bf(cf[r] * sm[r]);
    __builtin_amdgcn_wave_barrier();
    bf16x8 ap  = *(const bf16x8*)&pb[wv][lm][ko];
    bf16x8 vf0 = *(const bf16x8*)&vT[wv][lm][ko];
    bf16x8 vf1 = *(const bf16x8*)&vT[wv][16 + lm][ko];
    f32x4 o0 = __builtin_amdgcn_mfma_f32_16x16x32_bf16(ap, vf0, zero, 0, 0, 0);
    f32x4 o1 = __builtin_amdgcn_mfma_f32_16x16x32_bf16(ap, vf1, zero, 0, 0, 0);
    #pragma unroll
    for (int r = 0; r < 4; ++r) {
        int row = q4 + r;
        if (row < 13) {
            size_t ro = (size_t)(base + row * step) * N3 + h * 32;
            qkv[ro + lm]      = f2bf(o0[r]);
            qkv[ro + 16 + lm] = f2bf(o1[r]);
        }
    }
}

// ---------------------------------------------------------------- proj GEMM: tok = resid + attn @ P + pb
// grid (4, 468): n fastest. Swizzled global_load_lds staging; A row stride is N3.
__global__ __launch_bounds__(256) void proj_gemm(
    const unsigned short* __restrict__ attn,   // qkv buffer, cols [0,512), row stride 1536
    const unsigned short* __restrict__ pT, const float* __restrict__ pb,
    const float* __restrict__ resid, float* __restrict__ tok)
{
    __shared__ alignas(16) unsigned short As[128][64];
    __shared__ alignas(16) unsigned short Bs[128][64];
    const int n0 = blockIdx.x * 128, m0 = blockIdx.y * 128;
    const int tid = threadIdx.x, lane = tid & 63, wv = tid >> 6;
    const int wm = (wv >> 1) * 64, wn = (wv & 1) * 64;
    const int srow = lane >> 3;
    const int scol = (((lane & 7) ^ srow) << 3);
    f32x4 acc[4][4] = {};

    for (int k0 = 0; k0 < 512; k0 += 64) {
        #pragma unroll
        for (int i = 0; i < 4; ++i) {
            int c = i * 4 + wv;
            int r = c * 8 + srow;
            gload16(&As[c * 8][0], &attn[(size_t)(m0 + r) * N3 + k0 + scol]);
            gload16(&Bs[c * 8][0], &pT [(size_t)(n0 + r) * 512 + k0 + scol]);
        }
        __syncthreads();
        const int ko = (lane >> 4) * 8, lm = lane & 15, sw = lm & 7;
        #pragma unroll
        for (int kk = 0; kk < 64; kk += 32) {
            const int cA = ((((kk + ko) >> 3) ^ sw) << 3);
            bf16x8 af[4], bfr[4];
            #pragma unroll
            for (int mi = 0; mi < 4; ++mi) af[mi]  = *(const bf16x8*)&As[wm + mi * 16 + lm][cA];
            #pragma unroll
            for (int ni = 0; ni < 4; ++ni) bfr[ni] = *(const bf16x8*)&Bs[wn + ni * 16 + lm][cA];
            #pragma unroll
            for (int mi = 0; mi < 4; ++mi)
                #pragma unroll
                for (int ni = 0; ni < 4; ++ni)
                    acc[mi][ni] = __builtin_amdgcn_mfma_f32_16x16x32_bf16(af[mi], bfr[ni], acc[mi][ni], 0, 0, 0);
        }
        __syncthreads();
    }
    const int cr = (lane >> 4) * 4, ccol = lane & 15;
    #pragma unroll
    for (int ni = 0; ni < 4; ++ni) {
        int col = n0 + wn + ni * 16 + ccol;
        float bb = pb[col];
        #pragma unroll
        for (int mi = 0; mi < 4; ++mi)
            #pragma unroll
            for (int r = 0; r < 4; ++r) {
                int row = m0 + wm + mi * 16 + cr + r;
                size_t a = (size_t)row * 512 + col;
                tok[a] = resid[a] + acc[mi][ni][r] + bb;   // residual (resid may alias tok)
            }
    }
}

// ---------------------------------------------------------------- launch
extern "C" void kernel_launch(void* const* d_in, const int* in_sizes, int n_in,
                              void* d_out, int out_size, void* d_ws, size_t ws_size,
                              hipStream_t stream) {
    const float* x        = (const float*)d_in[0];
    const float* lat_grid = (const float*)d_in[1];
    const float* lon_grid = (const float*)d_in[2];
    const float* qkv_w[3] = {(const float*)d_in[3], (const float*)d_in[5], (const float*)d_in[7]};
    const float* qkv_b[3] = {(const float*)d_in[4], (const float*)d_in[6], (const float*)d_in[8]};
    const float* proj_w   = (const float*)d_in[9];
    const float* proj_b   = (const float*)d_in[10];
    const float* g[3]     = {(const float*)d_in[11], (const float*)d_in[13], (const float*)d_in[15]};
    const float* bln[3]   = {(const float*)d_in[12], (const float*)d_in[14], (const float*)d_in[16]};
    float* tok = (float*)d_out;

    unsigned short* wT0 = (unsigned short*)d_ws;
    unsigned short* wT1 = wT0 + 1536 * 512;
    unsigned short* wT2 = wT1 + 1536 * 512;
    unsigned short* pT  = wT2 + 1536 * 512;
    unsigned short* lnb = pT + 512 * 512;
    unsigned short* qkv = lnb + (size_t)MTOK * 512;
    unsigned short* wT[3] = {wT0, wT1, wT2};

    transpose_w<<<dim3(8, 24), 256, 0, stream>>>(qkv_w[0], wT0, 1536);
    transpose_w<<<dim3(8, 24), 256, 0, stream>>>(qkv_w[1], wT1, 1536);
    transpose_w<<<dim3(8, 24), 256, 0, stream>>>(qkv_w[2], wT2, 1536);
    transpose_w<<<dim3(8, 8),  256, 0, stream>>>(proj_w, pT, 512);

    for (int b = 0; b < 3; ++b) {
        const float* src = (b == 0) ? x : tok;
        ln_apply<<<MTOK / 4, 256, 0, stream>>>(src, g[b], bln[b], lnb);
        qkv_gemm<<<dim3(N3 / 128, MTOK / 128), 256, 0, stream>>>(lnb, wT[b], qkv_b[b], qkv);
        if (b == 0)
            attn_big<48, 0><<<dim3(L_DIM * W_DIM, NH), 256, 0, stream>>>(qkv, lat_grid, lon_grid);
        else if (b == 1)
            attn_big<96, 1><<<dim3(L_DIM * H_DIM, NH), 256, 0, stream>>>(qkv, lat_grid, lon_grid);
        else
            attn_small<<<(H_DIM * W_DIM * NH) / 4, 256, 0, stream>>>(qkv);
        proj_gemm<<<dim3(512 / 128, MTOK / 128), 256, 0, stream>>>(qkv, pT, proj_b, src, tok);
    }
}